// Round 5
// baseline (3073.103 us; speedup 1.0000x reference)
//
#include <hip/hip_runtime.h>
#include <hip/hip_bf16.h>

// CTRNN on MI355X.
//   out layout (fp32): output[512][128][1024] | hidden[128][1024] | ip[512][128][1024]
// Phase 1: cvt W_in fp32->bf16 (ws)
// Phase 2: ip = x @ W_in^T + b_in   (bf16 MFMA, fp32 out -> d_out seg3)
// Phase 3: persistent recurrent kernel, 128 blocks = 8 batch-tiles x 16 H-tiles.
//          W_hh slice in VGPRs. h exchanged via a depth-2 ring of SELF-VALIDATING
//          tagged dwords ((bf16<<16)|step+1), device-coherent sc0+sc1 path.
//          No flags, no producer drain, no startup barrier: consumers
//          speculatively load and retry until every dword's tag matches.

typedef __attribute__((ext_vector_type(8))) short short8;
typedef __attribute__((ext_vector_type(4))) float f32x4;
typedef __attribute__((ext_vector_type(4))) uint  uint4v;

#define S_LEN 512
#define BATCH 128
#define IN_DIM 512
#define HID 1024

__device__ __forceinline__ ushort f2bf(float f) {
    __hip_bfloat16 h = __float2bfloat16(f);
    return *reinterpret_cast<ushort*>(&h);
}

// ---------------- W_in conversion ----------------
__global__ void cvt_win(const float* __restrict__ win, ushort* __restrict__ win_bf) {
    int i = blockIdx.x * blockDim.x + threadIdx.x;
    if (i < HID * IN_DIM) win_bf[i] = f2bf(win[i]);
}

// ---------------- input projection GEMM ----------------
__global__ __launch_bounds__(256) void ip_gemm(const float* __restrict__ x,
                                               const ushort* __restrict__ winb,
                                               const float* __restrict__ b_in,
                                               float* __restrict__ ip) {
    __shared__ __align__(16) ushort As[64 * 32];
    __shared__ __align__(16) ushort Bs[64 * 32];
    const int tid  = threadIdx.x;
    const int lane = tid & 63;
    const int w    = tid >> 6;
    const int mt   = blockIdx.x >> 4;
    const int nt   = blockIdx.x & 15;
    const long Mbase = (long)mt * 64;
    const int  Nbase = nt * 64;

    const int sr = tid >> 2;
    const int sk = (tid & 3) * 8;

    f32x4 acc0 = {0,0,0,0}, acc1 = {0,0,0,0}, acc2 = {0,0,0,0}, acc3 = {0,0,0,0};

    const int ar    = w * 16 + (lane & 15);
    const int kb    = ((lane >> 4) * 8) * 2;
    const int aoff  = (ar * 64 + kb) ^ ((ar & 7) << 4);
    const int boff  = ((lane & 15) * 64 + kb) ^ (((lane & 15) & 7) << 4);
    const int soff  = (sr * 64 + sk * 2) ^ ((sr & 7) << 4);

    for (int kc = 0; kc < IN_DIM; kc += 32) {
        const float* ap = x + (Mbase + sr) * IN_DIM + kc + sk;
        f32x4 av0 = *(const f32x4*)ap;
        f32x4 av1 = *(const f32x4*)(ap + 4);
        short8 bv = *(const short8*)(winb + (size_t)(Nbase + sr) * IN_DIM + kc + sk);
        short8 av;
#pragma unroll
        for (int j = 0; j < 4; ++j) {
            av[j]     = (short)f2bf(av0[j]);
            av[4 + j] = (short)f2bf(av1[j]);
        }
        __syncthreads();
        *(short8*)((char*)As + soff) = av;
        *(short8*)((char*)Bs + soff) = bv;
        __syncthreads();

        short8 a  = *(const short8*)((char*)As + aoff);
        short8 b0 = *(const short8*)((char*)Bs + boff);
        short8 b1 = *(const short8*)((char*)Bs + boff + 1024);
        short8 b2 = *(const short8*)((char*)Bs + boff + 2048);
        short8 b3 = *(const short8*)((char*)Bs + boff + 3072);
        acc0 = __builtin_amdgcn_mfma_f32_16x16x32_bf16(a, b0, acc0, 0, 0, 0);
        acc1 = __builtin_amdgcn_mfma_f32_16x16x32_bf16(a, b1, acc1, 0, 0, 0);
        acc2 = __builtin_amdgcn_mfma_f32_16x16x32_bf16(a, b2, acc2, 0, 0, 0);
        acc3 = __builtin_amdgcn_mfma_f32_16x16x32_bf16(a, b3, acc3, 0, 0, 0);
    }

    const int nl   = lane & 15;
    const int mrow = w * 16 + (lane >> 4) * 4;
    const float bi0 = b_in[Nbase + nl];
    const float bi1 = b_in[Nbase + 16 + nl];
    const float bi2 = b_in[Nbase + 32 + nl];
    const float bi3 = b_in[Nbase + 48 + nl];
#pragma unroll
    for (int j = 0; j < 4; ++j) {
        float* op = ip + (Mbase + mrow + j) * HID + Nbase + nl;
        op[0]  = acc0[j] + bi0;
        op[16] = acc1[j] + bi1;
        op[32] = acc2[j] + bi2;
        op[48] = acc3[j] + bi3;
    }
}

// ---------------- persistent recurrent kernel ----------------
// grid = 128 blocks: bi = blockIdx&7 (16 batch rows), ni = blockIdx>>3 (64 H cols).
// hbt: uint32[2][128][1024] tagged ring, tag = step+1 in low 16 bits.
__global__ __launch_bounds__(256, 1) void ctrnn_rec(const float* __restrict__ whh,
                                                    const float* __restrict__ b_hh,
                                                    const float* __restrict__ ip,
                                                    float* __restrict__ out,
                                                    float* __restrict__ hidden,
                                                    uint* __restrict__ hbt) {
    const int tid  = threadIdx.x;
    const int lane = tid & 63;
    const int w    = tid >> 6;
    const int bi   = blockIdx.x & 7;
    const int ni   = blockIdx.x >> 3;

    __shared__ __align__(16) ushort As[16 * 1024];   // 32 KB staged h rows
    __shared__ __align__(16) float  tile[16][68];    // transpose tile (padded)

    const int ncol = lane & 15;
    const int n_g  = ni * 64 + w * 16 + ncol;
    const int kgrp = (lane >> 4) * 8;

    // W_hh fragments converted from fp32 at startup
    short8 wf[32];
#pragma unroll
    for (int kk = 0; kk < 32; ++kk) {
        const float* wp = whh + (size_t)n_g * HID + kk * 32 + kgrp;
        f32x4 w0 = *(const f32x4*)wp;
        f32x4 w1 = *(const f32x4*)(wp + 4);
        short8 f;
#pragma unroll
        for (int j = 0; j < 4; ++j) {
            f[j]     = (short)f2bf(w0[j]);
            f[4 + j] = (short)f2bf(w1[j]);
        }
        wf[kk] = f;
    }
    const float bias = b_hh[n_g];

    const int crow = tid & 15;            // consumer staging row
    const int cc0  = (tid >> 4) * 64;     // consumer col base (64 tagged dwords)
    const int arow  = lane & 15;
    const int arxor = (arow & 7) << 4;
    const int tr = tid >> 4, tc4 = (tid & 15) * 4;  // transpose-read map
    const int bg0 = bi * 16 + (lane >> 4) * 4;

    f32x4 hprev = {0, 0, 0, 0};
    f32x4 xtv;
#pragma unroll
    for (int j = 0; j < 4; ++j)
        xtv[j] = ip[(size_t)(bg0 + j) * HID + n_g];   // t = 0

    for (int t = 0; t < S_LEN; ++t) {
        f32x4 ac0 = {0,0,0,0}, ac1 = {0,0,0,0}, ac2 = {0,0,0,0}, ac3 = {0,0,0,0};
        if (t > 0) {
            // ---- speculative tagged load + validate-retry ----
            const uint exp = (uint)t;   // producer at t-1 stored tag t
            const uint* src = hbt + (size_t)((t - 1) & 1) * BATCH * HID
                              + (size_t)(bi * 16 + crow) * HID + cc0;
            uint4v v[16];
            long spin = 0;
            for (;;) {
#pragma unroll
                for (int i = 0; i < 16; ++i)
                    asm volatile("global_load_dwordx4 %0, %1, off sc0 sc1"
                                 : "=v"(v[i]) : "v"(src + i * 4) : "memory");
                asm volatile("s_waitcnt vmcnt(0)" ::: "memory");
                uint bad = 0;
#pragma unroll
                for (int i = 0; i < 16; ++i)
                    bad |= ((v[i][0] ^ exp) | (v[i][1] ^ exp) |
                            (v[i][2] ^ exp) | (v[i][3] ^ exp)) & 0xFFFFu;
                if (__all(bad == 0)) break;
                if (++spin > (1L << 14)) break;   // safety bail-out
                __builtin_amdgcn_s_sleep(1);
            }

            // ---- repack (strip tags, pair bf16) -> LDS (swizzled) ----
#pragma unroll
            for (int i = 0; i < 16; i += 2) {
                uint4v pk;
                pk[0] = (v[i][0] >> 16)     | (v[i][1]     & 0xFFFF0000u);
                pk[1] = (v[i][2] >> 16)     | (v[i][3]     & 0xFFFF0000u);
                pk[2] = (v[i + 1][0] >> 16) | (v[i + 1][1] & 0xFFFF0000u);
                pk[3] = (v[i + 1][2] >> 16) | (v[i + 1][3] & 0xFFFF0000u);
                int off = (crow * 2048 + (cc0 + i * 4) * 2) ^ ((crow & 7) << 4);
                *(uint4v*)((char*)As + off) = pk;
            }
            __syncthreads();

#define AREAD(kk) (*(const short8*)((char*)As + ((arow * 2048 + ((kk) * 32 + kgrp) * 2) ^ arxor)))
#pragma unroll
            for (int kk = 0; kk < 32; kk += 4) {
                ac0 = __builtin_amdgcn_mfma_f32_16x16x32_bf16(AREAD(kk + 0), wf[kk + 0], ac0, 0, 0, 0);
                ac1 = __builtin_amdgcn_mfma_f32_16x16x32_bf16(AREAD(kk + 1), wf[kk + 1], ac1, 0, 0, 0);
                ac2 = __builtin_amdgcn_mfma_f32_16x16x32_bf16(AREAD(kk + 2), wf[kk + 2], ac2, 0, 0, 0);
                ac3 = __builtin_amdgcn_mfma_f32_16x16x32_bf16(AREAD(kk + 3), wf[kk + 3], ac3, 0, 0, 0);
            }
#undef AREAD
        }

        // ---- epilogue: h update in C-frag regs -> LDS transpose ----
#pragma unroll
        for (int j = 0; j < 4; ++j) {
            float acc = (ac0[j] + ac1[j]) + (ac2[j] + ac3[j]);
            float hn  = xtv[j] + acc + bias;
            hn        = hn > 0.0f ? hn : 0.0f;
            float h   = hprev[j] * 0.8f + 0.2f * hn;
            hprev[j]  = h;
            tile[(lane >> 4) * 4 + j][w * 16 + ncol] = h;
        }
        __syncthreads();

        // ---- wide read-back, tagged publish (single 16B store, no drain) ----
        f32x4 hw = *(const f32x4*)&tile[tr][tc4];
        uint4v pk4;
        const uint tag = (uint)(t + 1);
#pragma unroll
        for (int j = 0; j < 4; ++j)
            pk4[j] = ((uint)f2bf(hw[j]) << 16) | tag;
        uint* hdst = hbt + (size_t)(t & 1) * BATCH * HID
                     + (size_t)(bi * 16 + tr) * HID + ni * 64 + tc4;
        asm volatile("global_store_dwordx4 %0, %1, off sc0 sc1" :: "v"(hdst), "v"(pk4) : "memory");

        // ---- prefetch next xt into the retry window ----
        if (t + 1 < S_LEN) {
            const float* ipn = ip + (size_t)(t + 1) * BATCH * HID;
#pragma unroll
            for (int j = 0; j < 4; ++j)
                xtv[j] = ipn[(size_t)(bg0 + j) * HID + n_g];
        }

        // ---- cached wide stores (off the critical path) ----
        float* od = out + (size_t)t * BATCH * HID + (size_t)(bi * 16 + tr) * HID + ni * 64 + tc4;
        *(f32x4*)od = hw;
        if (t == S_LEN - 1) {
            float* hd = hidden + (size_t)(bi * 16 + tr) * HID + ni * 64 + tc4;
            *(f32x4*)hd = hw;
        }
    }
}

extern "C" void kernel_launch(void* const* d_in, const int* in_sizes, int n_in,
                              void* d_out, int out_size, void* d_ws, size_t ws_size,
                              hipStream_t stream) {
    const float* x    = (const float*)d_in[0];
    const float* W_in = (const float*)d_in[1];
    const float* b_in = (const float*)d_in[2];
    const float* W_hh = (const float*)d_in[3];
    const float* b_hh = (const float*)d_in[4];

    float* out    = (float*)d_out;
    float* hidden = out + (size_t)S_LEN * BATCH * HID;
    float* ip     = hidden + (size_t)BATCH * HID;

    char* ws = (char*)d_ws;
    ushort* win_bf = (ushort*)ws;                               // 1 MB
    uint*   hbt    = (uint*)(ws + (size_t)1 * 1024 * 1024);     // 1 MB tagged h ring

    cvt_win<<<(HID * IN_DIM) / 256, 256, 0, stream>>>(W_in, win_bf);
    ip_gemm<<<(65536 / 64) * (HID / 64), 256, 0, stream>>>(x, win_bf, b_in, ip);
    // tags start at 1; zero the ring so stale tags from a previous replay can't validate
    hipMemsetAsync(hbt, 0, (size_t)2 * BATCH * HID * sizeof(uint), stream);
    ctrnn_rec<<<128, 256, 0, stream>>>(W_hh, b_hh, ip, out, hidden, hbt);
}

// Round 6
// 1838.312 us; speedup vs baseline: 1.6717x; 1.6717x over previous
//
#include <hip/hip_runtime.h>
#include <hip/hip_bf16.h>

// CTRNN on MI355X.
//   out layout (fp32): output[512][128][1024] | hidden[128][1024] | ip[512][128][1024]
// Phase 1: cvt W_in fp32->bf16 (ws)
// Phase 2: ip = x @ W_in^T + b_in   (bf16 MFMA, fp32 out -> d_out seg3)
// Phase 3: persistent recurrent kernel, 128 blocks = 8 batch-tiles x 16 H-tiles.
//          K-SPLIT design: wave w owns k-range [w*256,(w+1)*256) = exactly 4
//          producer blocks. Poll 4 block-flags -> load A-frags DIRECTLY from
//          global (no LDS staging) -> 32 MFMA partials -> LDS f32 reduction ->
//          epilogue in (b,n)-contiguous layout -> 8B publish + 1 block flag.
//          Protocol (proven R3): data sc0 sc1 -> vmcnt(0) -> barrier -> flag.

typedef __attribute__((ext_vector_type(8))) short short8;
typedef __attribute__((ext_vector_type(4))) float f32x4;

#define S_LEN 512
#define BATCH 128
#define IN_DIM 512
#define HID 1024

__device__ __forceinline__ ushort f2bf(float f) {
    __hip_bfloat16 h = __float2bfloat16(f);
    return *reinterpret_cast<ushort*>(&h);
}

// ---------------- W_in conversion ----------------
__global__ void cvt_win(const float* __restrict__ win, ushort* __restrict__ win_bf) {
    int i = blockIdx.x * blockDim.x + threadIdx.x;
    if (i < HID * IN_DIM) win_bf[i] = f2bf(win[i]);
}

// ---------------- input projection GEMM ----------------
__global__ __launch_bounds__(256) void ip_gemm(const float* __restrict__ x,
                                               const ushort* __restrict__ winb,
                                               const float* __restrict__ b_in,
                                               float* __restrict__ ip) {
    __shared__ __align__(16) ushort As[64 * 32];
    __shared__ __align__(16) ushort Bs[64 * 32];
    const int tid  = threadIdx.x;
    const int lane = tid & 63;
    const int w    = tid >> 6;
    const int mt   = blockIdx.x >> 4;
    const int nt   = blockIdx.x & 15;
    const long Mbase = (long)mt * 64;
    const int  Nbase = nt * 64;

    const int sr = tid >> 2;
    const int sk = (tid & 3) * 8;

    f32x4 acc0 = {0,0,0,0}, acc1 = {0,0,0,0}, acc2 = {0,0,0,0}, acc3 = {0,0,0,0};

    const int ar    = w * 16 + (lane & 15);
    const int kb    = ((lane >> 4) * 8) * 2;
    const int aoff  = (ar * 64 + kb) ^ ((ar & 7) << 4);
    const int boff  = ((lane & 15) * 64 + kb) ^ (((lane & 15) & 7) << 4);
    const int soff  = (sr * 64 + sk * 2) ^ ((sr & 7) << 4);

    for (int kc = 0; kc < IN_DIM; kc += 32) {
        const float* ap = x + (Mbase + sr) * IN_DIM + kc + sk;
        f32x4 av0 = *(const f32x4*)ap;
        f32x4 av1 = *(const f32x4*)(ap + 4);
        short8 bv = *(const short8*)(winb + (size_t)(Nbase + sr) * IN_DIM + kc + sk);
        short8 av;
#pragma unroll
        for (int j = 0; j < 4; ++j) {
            av[j]     = (short)f2bf(av0[j]);
            av[4 + j] = (short)f2bf(av1[j]);
        }
        __syncthreads();
        *(short8*)((char*)As + soff) = av;
        *(short8*)((char*)Bs + soff) = bv;
        __syncthreads();

        short8 a  = *(const short8*)((char*)As + aoff);
        short8 b0 = *(const short8*)((char*)Bs + boff);
        short8 b1 = *(const short8*)((char*)Bs + boff + 1024);
        short8 b2 = *(const short8*)((char*)Bs + boff + 2048);
        short8 b3 = *(const short8*)((char*)Bs + boff + 3072);
        acc0 = __builtin_amdgcn_mfma_f32_16x16x32_bf16(a, b0, acc0, 0, 0, 0);
        acc1 = __builtin_amdgcn_mfma_f32_16x16x32_bf16(a, b1, acc1, 0, 0, 0);
        acc2 = __builtin_amdgcn_mfma_f32_16x16x32_bf16(a, b2, acc2, 0, 0, 0);
        acc3 = __builtin_amdgcn_mfma_f32_16x16x32_bf16(a, b3, acc3, 0, 0, 0);
    }

    const int nl   = lane & 15;
    const int mrow = w * 16 + (lane >> 4) * 4;
    const float bi0 = b_in[Nbase + nl];
    const float bi1 = b_in[Nbase + 16 + nl];
    const float bi2 = b_in[Nbase + 32 + nl];
    const float bi3 = b_in[Nbase + 48 + nl];
#pragma unroll
    for (int j = 0; j < 4; ++j) {
        float* op = ip + (Mbase + mrow + j) * HID + Nbase + nl;
        op[0]  = acc0[j] + bi0;
        op[16] = acc1[j] + bi1;
        op[32] = acc2[j] + bi2;
        op[48] = acc3[j] + bi3;
    }
}

// ---------------- persistent recurrent kernel ----------------
// grid = 128 blocks: bi = blockIdx&7 (16 batch rows), ni = blockIdx>>3 (64 H cols).
// flags[((t*8+bi)*16 + ni)*4]: block (bi,ni) published h[t] (16B-padded words).
__global__ __launch_bounds__(256, 1) void ctrnn_rec(const float* __restrict__ whh,
                                                    const float* __restrict__ b_hh,
                                                    const float* __restrict__ ip,
                                                    float* __restrict__ out,
                                                    float* __restrict__ hidden,
                                                    ushort* __restrict__ hbuf,
                                                    int* __restrict__ flags) {
    const int tid  = threadIdx.x;
    const int lane = tid & 63;
    const int w    = tid >> 6;
    const int bi   = blockIdx.x & 7;
    const int ni   = blockIdx.x >> 3;

    __shared__ __align__(16) float P[4][16][68];   // 17.4 KB K-partials (padded)

    // ---- MFMA-role mapping: wave w owns k in [w*256, w*256+256) ----
    const int arow = lane & 15;          // A row = batch within tile; W col = n within group
    const int kgrp = (lane >> 4) * 8;    // k sub-offset within 32-chunk

    // W_hh fragments: wf[g][kk] = W[ni*64+g*16+arow][w*256 + kk*32 + kgrp + 0..7]
    short8 wf[4][8];
#pragma unroll
    for (int g = 0; g < 4; ++g)
#pragma unroll
        for (int kk = 0; kk < 8; ++kk) {
            const float* wp = whh + (size_t)(ni * 64 + g * 16 + arow) * HID
                              + w * 256 + kk * 32 + kgrp;
            f32x4 w0 = *(const f32x4*)wp;
            f32x4 w1 = *(const f32x4*)(wp + 4);
            short8 f;
#pragma unroll
            for (int j = 0; j < 4; ++j) {
                f[j]     = (short)f2bf(w0[j]);
                f[4 + j] = (short)f2bf(w1[j]);
            }
            wf[g][kk] = f;
        }

    // ---- epilogue-role mapping: thread owns (b = tid>>4, n0 = (tid&15)*4) ----
    const int eb = tid >> 4;
    const int n0 = (tid & 15) * 4;
    const f32x4 bias4 = *(const f32x4*)&b_hh[ni * 64 + n0];
    f32x4 hprev = {0, 0, 0, 0};
    f32x4 xtv   = *(const f32x4*)&ip[(size_t)(bi * 16 + eb) * HID + ni * 64 + n0];

    for (int t = 0; t < S_LEN; ++t) {
        f32x4 acc = {0, 0, 0, 0};
        if (t > 0) {
            // ---- poll this wave's 4 producer block-flags (lanes 0-3) ----
            if (lane < 4) {
                const int* fl = flags + (((size_t)(t - 1) * 8 + bi) * 16 + w * 4 + lane) * 4;
                long spin = 0;
                for (;;) {
                    int v;
                    asm volatile("global_load_dword %0, %1, off sc0 sc1\n\ts_waitcnt vmcnt(0)"
                                 : "=v"(v) : "v"(fl) : "memory");
                    if (__all(v != 0)) break;
                    if (++spin > (1L << 20)) break;
                }
            }

            // ---- load A-frags directly from global (2 KB per wave) ----
            const ushort* hs = hbuf + (size_t)((t - 1) & 1) * BATCH * HID
                               + (size_t)(bi * 16 + arow) * HID + w * 256 + kgrp;
            short8 af0, af1, af2, af3, af4, af5, af6, af7;
#define LDA(reg, kk)                                                            \
            asm volatile("global_load_dwordx4 %0, %1, off sc0 sc1"              \
                         : "=v"(reg) : "v"(hs + (kk) * 32) : "memory")
            LDA(af0, 0); LDA(af1, 1); LDA(af2, 2); LDA(af3, 3);
            LDA(af4, 4); LDA(af5, 5); LDA(af6, 6); LDA(af7, 7);
#undef LDA
            asm volatile("s_waitcnt vmcnt(0)" ::: "memory");
            __builtin_amdgcn_sched_barrier(0);

            // ---- 32 MFMAs: 4 n-groups x 8 k-chunks (K-partial accs) ----
            f32x4 a0 = {0,0,0,0}, a1 = {0,0,0,0}, a2 = {0,0,0,0}, a3 = {0,0,0,0};
#define STEP(afk, kk)                                                               \
            a0 = __builtin_amdgcn_mfma_f32_16x16x32_bf16(afk, wf[0][kk], a0, 0, 0, 0); \
            a1 = __builtin_amdgcn_mfma_f32_16x16x32_bf16(afk, wf[1][kk], a1, 0, 0, 0); \
            a2 = __builtin_amdgcn_mfma_f32_16x16x32_bf16(afk, wf[2][kk], a2, 0, 0, 0); \
            a3 = __builtin_amdgcn_mfma_f32_16x16x32_bf16(afk, wf[3][kk], a3, 0, 0, 0)
            STEP(af0, 0); STEP(af1, 1); STEP(af2, 2); STEP(af3, 3);
            STEP(af4, 4); STEP(af5, 5); STEP(af6, 6); STEP(af7, 7);
#undef STEP

            // ---- write K-partials to LDS (C/D map: row=(lane>>4)*4+j, col=arow) ----
#pragma unroll
            for (int j = 0; j < 4; ++j) {
                const int br = (lane >> 4) * 4 + j;
                P[w][br][arow]      = a0[j];
                P[w][br][16 + arow] = a1[j];
                P[w][br][32 + arow] = a2[j];
                P[w][br][48 + arow] = a3[j];
            }
            __syncthreads();

            // ---- reduce 4 wave-partials for (eb, n0..n0+3) ----
            f32x4 r0 = *(const f32x4*)&P[0][eb][n0];
            f32x4 r1 = *(const f32x4*)&P[1][eb][n0];
            f32x4 r2 = *(const f32x4*)&P[2][eb][n0];
            f32x4 r3 = *(const f32x4*)&P[3][eb][n0];
            acc = (r0 + r1) + (r2 + r3);
        }

        // ---- epilogue in (b,n)-contiguous layout ----
        f32x4 hw;
#pragma unroll
        for (int j = 0; j < 4; ++j) {
            float hn = xtv[j] + acc[j] + bias4[j];
            hn       = hn > 0.0f ? hn : 0.0f;
            hw[j]    = hprev[j] * 0.8f + 0.2f * hn;
        }
        hprev = hw;

        // ---- publish 8B bf16 (bypass) -> drain -> barrier -> block flag ----
        uint2 pk;
        pk.x = (uint)f2bf(hw[0]) | ((uint)f2bf(hw[1]) << 16);
        pk.y = (uint)f2bf(hw[2]) | ((uint)f2bf(hw[3]) << 16);
        ushort* hdst = hbuf + (size_t)(t & 1) * BATCH * HID
                       + (size_t)(bi * 16 + eb) * HID + ni * 64 + n0;
        asm volatile("global_store_dwordx2 %0, %1, off sc0 sc1" :: "v"(hdst), "v"(pk) : "memory");
        asm volatile("s_waitcnt vmcnt(0)" ::: "memory");
        __syncthreads();
        if (tid == 0) {
            int one = 1;
            int* fdst = flags + (((size_t)t * 8 + bi) * 16 + ni) * 4;
            asm volatile("global_store_dword %0, %1, off sc0 sc1" :: "v"(fdst), "v"(one) : "memory");
        }

        // ---- off-critical-path: out/hidden stores + next xt prefetch ----
        float* od = out + (size_t)t * BATCH * HID + (size_t)(bi * 16 + eb) * HID + ni * 64 + n0;
        *(f32x4*)od = hw;
        if (t == S_LEN - 1) {
            float* hd = hidden + (size_t)(bi * 16 + eb) * HID + ni * 64 + n0;
            *(f32x4*)hd = hw;
        }
        if (t + 1 < S_LEN)
            xtv = *(const f32x4*)&ip[(size_t)(t + 1) * BATCH * HID
                                     + (size_t)(bi * 16 + eb) * HID + ni * 64 + n0];
    }
}

extern "C" void kernel_launch(void* const* d_in, const int* in_sizes, int n_in,
                              void* d_out, int out_size, void* d_ws, size_t ws_size,
                              hipStream_t stream) {
    const float* x    = (const float*)d_in[0];
    const float* W_in = (const float*)d_in[1];
    const float* b_in = (const float*)d_in[2];
    const float* W_hh = (const float*)d_in[3];
    const float* b_hh = (const float*)d_in[4];

    float* out    = (float*)d_out;
    float* hidden = out + (size_t)S_LEN * BATCH * HID;
    float* ip     = hidden + (size_t)BATCH * HID;

    char* ws = (char*)d_ws;
    ushort* win_bf = (ushort*)ws;                               // 1 MB
    ushort* hbuf   = (ushort*)(ws + (size_t)1 * 1024 * 1024);   // 512 KB h ring
    int*    flags  = (int*)(ws + (size_t)2 * 1024 * 1024);      // 1 MB block flags (16B pad)

    cvt_win<<<(HID * IN_DIM) / 256, 256, 0, stream>>>(W_in, win_bf);
    ip_gemm<<<(65536 / 64) * (HID / 64), 256, 0, stream>>>(x, win_bf, b_in, ip);
    hipMemsetAsync(flags, 0, (size_t)S_LEN * 8 * 16 * 4 * sizeof(int), stream);
    ctrnn_rec<<<128, 256, 0, stream>>>(W_hh, b_hh, ip, out, hidden, hbuf, flags);
}